// Round 5
// baseline (371.187 us; speedup 1.0000x reference)
//
#include <hip/hip_runtime.h>

#define D_IN 150528
#define FEAT 256
#define HID 64
#define T 4
#define B 8
#define NROWS 1280            // 5 * 256 rows (W1 + 4x dW1)
#define TILE 1024             // floats per K tile
#define RPT 4                 // rows per thread
#define ROWS_PER_BLOCK 64     // 16 groups x RPT
#define NRB 20                // 1280 / 64
#define D4 (D_IN / 4)         // 37632 float4 per x row

// ---------------- stage 1: the 5 batched GEMVs over K=150528 ----------------
// grid (ksplit, 20), block 256, NO LDS, NO barriers: x (4.8 MB) is L2-resident
// and the 4 row-groups of a wave read identical x addresses (segment broadcast).
// Each thread: 4 rows x 8 batch; 12 float4 loads feed 128 FMAs per j-iter.
__global__ __launch_bounds__(256) void stage1(
    const float* __restrict__ x, const float* __restrict__ W1,
    const float* __restrict__ dW1, float* __restrict__ partial, int tiles) {
  const int ks  = blockIdx.x;
  const int rg  = blockIdx.y;                         // 0..19
  const int tid = threadIdx.x;
  const int sub  = tid & 15;                          // lane within row-group
  const int rloc = tid >> 4;                          // 0..15
  const int r0 = rg * ROWS_PER_BLOCK + rloc * RPT;    // 4 consecutive rows
  const float* rowp[RPT];
#pragma unroll
  for (int i = 0; i < RPT; ++i) {
    int r = r0 + i, m = r >> 8, f = r & 255;
    rowp[i] = (m == 0) ? (W1 + (size_t)f * D_IN)
                       : (dW1 + ((size_t)(m - 1) * FEAT + f) * D_IN);
  }
  const int kbase0 = ks * tiles * TILE;

  float acc[RPT][B];
#pragma unroll
  for (int i = 0; i < RPT; ++i)
#pragma unroll
    for (int b = 0; b < B; ++b) acc[i][b] = 0.f;

  for (int t = 0; t < tiles; ++t) {
    const int kbase = kbase0 + t * TILE;
    const float4* x4 = (const float4*)(x + kbase);    // + b*D4 + kk
#pragma unroll 4
    for (int j = 0; j < 16; ++j) {
      const int kk = sub + j * 16;                    // float4 index in tile
      float4 mv[RPT];
#pragma unroll
      for (int i = 0; i < RPT; ++i)
        mv[i] = ((const float4*)(rowp[i] + kbase))[kk];
      float4 xv[B];
#pragma unroll
      for (int b = 0; b < B; ++b) xv[b] = x4[b * D4 + kk];
#pragma unroll
      for (int b = 0; b < B; ++b)
#pragma unroll
        for (int i = 0; i < RPT; ++i)
          acc[i][b] += mv[i].x * xv[b].x + mv[i].y * xv[b].y +
                       mv[i].z * xv[b].z + mv[i].w * xv[b].w;
    }
  }
  // reduce across the 16 lanes of each row-group
#pragma unroll
  for (int i = 0; i < RPT; ++i)
#pragma unroll
    for (int b = 0; b < B; ++b) {
      float v = acc[i][b];
      v += __shfl_xor(v, 1, 16);
      v += __shfl_xor(v, 2, 16);
      v += __shfl_xor(v, 4, 16);
      v += __shfl_xor(v, 8, 16);
      acc[i][b] = v;
    }
  if (sub == 0) {
#pragma unroll
    for (int i = 0; i < RPT; ++i) {
      float* dst = partial + ((size_t)ks * NROWS + r0 + i) * B;
#pragma unroll
      for (int b = 0; b < B; ++b) dst[b] = acc[i][b];
    }
  }
}

// ---------------- stage 2: reduce K-splits, add biases ----------------
__global__ __launch_bounds__(256) void stage2(
    const float* __restrict__ partial, const float* __restrict__ b1,
    const float* __restrict__ db1, float* __restrict__ hp, int ksplit) {
  int idx = blockIdx.x * 256 + threadIdx.x;           // 0..10239
  int r = idx >> 3, b = idx & 7;
  int m = r >> 8, f = r & 255;
  float s = (m == 0) ? b1[f] : db1[(m - 1) * FEAT + f];
  for (int ks = 0; ks < ksplit; ++ks)
    s += partial[((size_t)ks * NROWS + r) * B + b];
  hp[idx] = s;                                        // hp[r][b]
}

// ---------------- stage 3a: h, base, MetaNet coefs, u ----------------
__global__ __launch_bounds__(256) void stage3a(
    const float* __restrict__ hp, const float* __restrict__ W2,
    const float* __restrict__ b2, const float* __restrict__ mW1,
    const float* __restrict__ mb1, const float* __restrict__ mW2,
    const float* __restrict__ mb2, float* __restrict__ h_out,
    float* __restrict__ base_out, float* __restrict__ coef_out,
    float* __restrict__ u_out) {
  __shared__ float h_l[B][FEAT];
  __shared__ float base_l[B][FEAT];
  __shared__ float mid_l[B][HID];
  __shared__ float c_l[B][T];
  const int tid = threadIdx.x;                        // == f (and == g)

  // h = relu(hpre)
  for (int b = 0; b < B; ++b) {
    float v = hp[(size_t)tid * B + b];                // m=0 rows: r == f
    float hv = v > 0.f ? v : 0.f;
    h_l[b][tid] = hv;
    h_out[b * FEAT + tid] = hv;
  }
  __syncthreads();

  // base[b][g] = b2[g] + h[b]·W2[g]
  {
    const float* wrow = W2 + (size_t)tid * FEAT;
    for (int b = 0; b < B; ++b) {
      float s = b2[tid];
      for (int f = 0; f < FEAT; ++f) s += h_l[b][f] * wrow[f];
      base_l[b][tid] = s;
      base_out[b * FEAT + tid] = s;
    }
  }
  __syncthreads();

  // mid[b][hid] = relu(mb1 + base[b]·mW1[hid])
  {
    int b = tid >> 5, h0 = tid & 31;
    for (int hh = h0; hh < HID; hh += 32) {
      float s = mb1[hh];
      const float* wrow = mW1 + hh * FEAT;
      for (int f = 0; f < FEAT; ++f) s += base_l[b][f] * wrow[f];
      mid_l[b][hh] = s > 0.f ? s : 0.f;
    }
  }
  __syncthreads();

  // coefs[b][t]
  if (tid < B * T) {
    int b = tid >> 2, t = tid & 3;
    float s = mb2[t];
    const float* wrow = mW2 + t * HID;
    for (int hh = 0; hh < HID; ++hh) s += mid_l[b][hh] * wrow[hh];
    c_l[b][t] = s;
    coef_out[tid] = s;
  }
  __syncthreads();

  // u[b][f] = (hpre>0) * sum_t c[b,t]*dhpre[t,b,f]
  for (int b = 0; b < B; ++b) {
    float hpre = hp[(size_t)tid * B + b];
    float s = 0.f;
    if (hpre > 0.f) {
#pragma unroll
      for (int t = 0; t < T; ++t)
        s += c_l[b][t] * hp[((size_t)(1 + t) * FEAT + tid) * B + b];
    }
    u_out[b * FEAT + tid] = s;
  }
}

// ---------------- stage 3b: final combine ----------------
__global__ __launch_bounds__(256) void stage3b(
    const float* __restrict__ h, const float* __restrict__ base,
    const float* __restrict__ coef, const float* __restrict__ u,
    const float* __restrict__ W2, const float* __restrict__ dW2,
    const float* __restrict__ db2, float* __restrict__ out) {
  __shared__ float h_l[FEAT];
  __shared__ float u_l[FEAT];
  const int b = blockIdx.x;
  const int g = threadIdx.x;
  h_l[g] = h[b * FEAT + g];
  u_l[g] = u[b * FEAT + g];
  __syncthreads();
  float c[T];
#pragma unroll
  for (int t = 0; t < T; ++t) c[t] = coef[b * T + t];
  float s = base[b * FEAT + g];
#pragma unroll
  for (int t = 0; t < T; ++t) s += c[t] * db2[t * FEAT + g];
  const float4* wrow = (const float4*)(W2 + (size_t)g * FEAT);
  const float4* hv4  = (const float4*)h_l;
  const float4* uv4  = (const float4*)u_l;
  float acc1 = 0.f;
  float acc2[T] = {0.f, 0.f, 0.f, 0.f};
  for (int f4 = 0; f4 < FEAT / 4; ++f4) {
    float4 w = wrow[f4];
    float4 uu = uv4[f4];
    acc1 += uu.x * w.x + uu.y * w.y + uu.z * w.z + uu.w * w.w;
    float4 hh = hv4[f4];
#pragma unroll
    for (int t = 0; t < T; ++t) {
      float4 dv = ((const float4*)(dW2 + (((size_t)t * FEAT) + g) * FEAT))[f4];
      acc2[t] += hh.x * dv.x + hh.y * dv.y + hh.z * dv.z + hh.w * dv.w;
    }
  }
  s += acc1;
#pragma unroll
  for (int t = 0; t < T; ++t) s += c[t] * acc2[t];
  out[b * FEAT + g] = s;
}

extern "C" void kernel_launch(void* const* d_in, const int* in_sizes, int n_in,
                              void* d_out, int out_size, void* d_ws, size_t ws_size,
                              hipStream_t stream) {
  const float* x   = (const float*)d_in[0];
  const float* W1  = (const float*)d_in[1];
  const float* b1  = (const float*)d_in[2];
  const float* W2  = (const float*)d_in[3];
  const float* b2  = (const float*)d_in[4];
  const float* mW1 = (const float*)d_in[5];
  const float* mb1 = (const float*)d_in[6];
  const float* mW2 = (const float*)d_in[7];
  const float* mb2 = (const float*)d_in[8];
  const float* dW1 = (const float*)d_in[9];
  const float* db1 = (const float*)d_in[10];
  const float* dW2 = (const float*)d_in[11];
  const float* db2 = (const float*)d_in[12];
  float* out = (float*)d_out;

  // 147 K-tiles of 1024; pick the largest split whose partials fit d_ws.
  int ksplit = 147, tiles = 1;
  {
    const int opts_ks[4]   = {147, 49, 21, 7};
    const int opts_tile[4] = {1, 3, 7, 21};
    for (int o = 0; o < 4; ++o) {
      size_t need = ((size_t)opts_ks[o] * NROWS * B + 10240 + 3 * 2048 + 32)
                    * sizeof(float);
      if (need <= ws_size) { ksplit = opts_ks[o]; tiles = opts_tile[o]; break; }
    }
  }

  float* ws   = (float*)d_ws;
  float* P    = ws;                              // [ksplit][1280][8]
  float* HP   = P + (size_t)ksplit * NROWS * B;  // [1280][8] = 10240
  float* H    = HP + 10240;                      // [8][256]
  float* BASE = H + 2048;                        // [8][256]
  float* U    = BASE + 2048;                     // [8][256]
  float* C    = U + 2048;                        // [8][4]

  stage1<<<dim3(ksplit, NRB), 256, 0, stream>>>(x, W1, dW1, P, tiles);
  stage2<<<40, 256, 0, stream>>>(P, b1, db1, HP, ksplit);
  stage3a<<<1, 256, 0, stream>>>(HP, W2, b2, mW1, mb1, mW2, mb2, H, BASE, C, U);
  stage3b<<<B, 256, 0, stream>>>(H, BASE, C, U, W2, dW2, db2, out);
}

// Round 6
// 320.437 us; speedup vs baseline: 1.1584x; 1.1584x over previous
//
#include <hip/hip_runtime.h>

#define D_IN 150528
#define FEAT 256
#define HID 64
#define T 4
#define B 8
#define NROWS 1280            // 5 * 256 rows (W1 + 4x dW1)
#define D4 37632              // D_IN / 4 float4 per row
#define KS 42                 // K splits
#define JSTEPS 14             // 588 / KS  (64-float4 steps per chunk)
#define RPW 8                 // rows per wave
#define RPB 32                // rows per block (4 waves)
#define NRB 40                // 1280 / 32

// ---------------- stage 1: the 5 batched GEMVs over K=150528 ----------------
// grid (42, 40), block 256 = 4 waves. Each wave owns 8 whole rows; all 64
// lanes load CONTIGUOUS float4 from one row per instruction (1 KB/instr,
// sequential 14 KB runs) -- DRAM-stream friendly. x chunk kept in registers
// (8 float4/thread, L2-hot) so x traffic = matrix traffic. No LDS/barriers.
__global__ __launch_bounds__(256) void stage1(
    const float* __restrict__ x, const float* __restrict__ W1,
    const float* __restrict__ dW1, float* __restrict__ partial) {
  const int ks   = blockIdx.x;                        // 0..41
  const int rb   = blockIdx.y;                        // 0..39
  const int wid  = threadIdx.x >> 6;                  // wave 0..3
  const int lane = threadIdx.x & 63;
  const int r0   = rb * RPB + wid * RPW;              // this wave's 8 rows
  const int kb4  = ks * (JSTEPS * 64);                // float4 offset in K

  const float4* rp[RPW];
#pragma unroll
  for (int i = 0; i < RPW; ++i) {
    int r = r0 + i, m = r >> 8, f = r & 255;
    const float* base = (m == 0) ? (W1 + (size_t)f * D_IN)
                                 : (dW1 + ((size_t)(m - 1) * FEAT + f) * D_IN);
    rp[i] = (const float4*)base + kb4;
  }
  const float4* x4 = (const float4*)x + kb4;          // + b*D4 + idx

  float acc[RPW][B];
#pragma unroll
  for (int i = 0; i < RPW; ++i)
#pragma unroll
    for (int b = 0; b < B; ++b) acc[i][b] = 0.f;

  for (int j = 0; j < JSTEPS; ++j) {
    const int idx = j * 64 + lane;
    float4 mv[RPW];
#pragma unroll
    for (int i = 0; i < RPW; ++i) mv[i] = rp[i][idx]; // 8x 1KB HBM streams
    float4 xv[B];
#pragma unroll
    for (int b = 0; b < B; ++b) xv[b] = x4[(size_t)b * D4 + idx]; // L2-hot
#pragma unroll
    for (int b = 0; b < B; ++b)
#pragma unroll
      for (int i = 0; i < RPW; ++i)
        acc[i][b] += mv[i].x * xv[b].x + mv[i].y * xv[b].y +
                     mv[i].z * xv[b].z + mv[i].w * xv[b].w;
  }

  // full-wave butterfly per (i,b); lane k keeps pair (k>>3, k&7)
  float outv = 0.f;
#pragma unroll
  for (int i = 0; i < RPW; ++i)
#pragma unroll
    for (int b = 0; b < B; ++b) {
      float v = acc[i][b];
      v += __shfl_xor(v, 1);
      v += __shfl_xor(v, 2);
      v += __shfl_xor(v, 4);
      v += __shfl_xor(v, 8);
      v += __shfl_xor(v, 16);
      v += __shfl_xor(v, 32);
      if (lane == i * B + b) outv = v;                // compile-time acc index
    }
  // rows r0..r0+7 x batch 0..7 are 64 consecutive floats: coalesced store
  partial[((size_t)ks * NROWS + r0) * B + lane] = outv;
}

// ---------------- stage 2: reduce K-splits, add biases ----------------
__global__ __launch_bounds__(256) void stage2(
    const float* __restrict__ partial, const float* __restrict__ b1,
    const float* __restrict__ db1, float* __restrict__ hp, int ksplit) {
  int idx = blockIdx.x * 256 + threadIdx.x;           // 0..10239
  int r = idx >> 3, b = idx & 7;
  int m = r >> 8, f = r & 255;
  float s = (m == 0) ? b1[f] : db1[(m - 1) * FEAT + f];
  for (int ks = 0; ks < ksplit; ++ks)
    s += partial[((size_t)ks * NROWS + r) * B + b];
  hp[idx] = s;                                        // hp[r][b]
}

// ---------------- stage 3a: h, base, MetaNet coefs, u ----------------
__global__ __launch_bounds__(256) void stage3a(
    const float* __restrict__ hp, const float* __restrict__ W2,
    const float* __restrict__ b2, const float* __restrict__ mW1,
    const float* __restrict__ mb1, const float* __restrict__ mW2,
    const float* __restrict__ mb2, float* __restrict__ h_out,
    float* __restrict__ base_out, float* __restrict__ coef_out,
    float* __restrict__ u_out) {
  __shared__ float h_l[B][FEAT];
  __shared__ float base_l[B][FEAT];
  __shared__ float mid_l[B][HID];
  __shared__ float c_l[B][T];
  const int tid = threadIdx.x;                        // == f (and == g)

  // h = relu(hpre)
  for (int b = 0; b < B; ++b) {
    float v = hp[(size_t)tid * B + b];                // m=0 rows: r == f
    float hv = v > 0.f ? v : 0.f;
    h_l[b][tid] = hv;
    h_out[b * FEAT + tid] = hv;
  }
  __syncthreads();

  // base[b][g] = b2[g] + h[b]·W2[g]
  {
    const float* wrow = W2 + (size_t)tid * FEAT;
    for (int b = 0; b < B; ++b) {
      float s = b2[tid];
      for (int f = 0; f < FEAT; ++f) s += h_l[b][f] * wrow[f];
      base_l[b][tid] = s;
      base_out[b * FEAT + tid] = s;
    }
  }
  __syncthreads();

  // mid[b][hid] = relu(mb1 + base[b]·mW1[hid])
  {
    int b = tid >> 5, h0 = tid & 31;
    for (int hh = h0; hh < HID; hh += 32) {
      float s = mb1[hh];
      const float* wrow = mW1 + hh * FEAT;
      for (int f = 0; f < FEAT; ++f) s += base_l[b][f] * wrow[f];
      mid_l[b][hh] = s > 0.f ? s : 0.f;
    }
  }
  __syncthreads();

  // coefs[b][t]
  if (tid < B * T) {
    int b = tid >> 2, t = tid & 3;
    float s = mb2[t];
    const float* wrow = mW2 + t * HID;
    for (int hh = 0; hh < HID; ++hh) s += mid_l[b][hh] * wrow[hh];
    c_l[b][t] = s;
    coef_out[tid] = s;
  }
  __syncthreads();

  // u[b][f] = (hpre>0) * sum_t c[b,t]*dhpre[t,b,f]
  for (int b = 0; b < B; ++b) {
    float hpre = hp[(size_t)tid * B + b];
    float s = 0.f;
    if (hpre > 0.f) {
#pragma unroll
      for (int t = 0; t < T; ++t)
        s += c_l[b][t] * hp[((size_t)(1 + t) * FEAT + tid) * B + b];
    }
    u_out[b * FEAT + tid] = s;
  }
}

// ---------------- stage 3b: final combine ----------------
__global__ __launch_bounds__(256) void stage3b(
    const float* __restrict__ h, const float* __restrict__ base,
    const float* __restrict__ coef, const float* __restrict__ u,
    const float* __restrict__ W2, const float* __restrict__ dW2,
    const float* __restrict__ db2, float* __restrict__ out) {
  __shared__ float h_l[FEAT];
  __shared__ float u_l[FEAT];
  const int b = blockIdx.x;
  const int g = threadIdx.x;
  h_l[g] = h[b * FEAT + g];
  u_l[g] = u[b * FEAT + g];
  __syncthreads();
  float c[T];
#pragma unroll
  for (int t = 0; t < T; ++t) c[t] = coef[b * T + t];
  float s = base[b * FEAT + g];
#pragma unroll
  for (int t = 0; t < T; ++t) s += c[t] * db2[t * FEAT + g];
  const float4* wrow = (const float4*)(W2 + (size_t)g * FEAT);
  const float4* hv4  = (const float4*)h_l;
  const float4* uv4  = (const float4*)u_l;
  float acc1 = 0.f;
  float acc2[T] = {0.f, 0.f, 0.f, 0.f};
  for (int f4 = 0; f4 < FEAT / 4; ++f4) {
    float4 w = wrow[f4];
    float4 uu = uv4[f4];
    acc1 += uu.x * w.x + uu.y * w.y + uu.z * w.z + uu.w * w.w;
    float4 hh = hv4[f4];
#pragma unroll
    for (int t = 0; t < T; ++t) {
      float4 dv = ((const float4*)(dW2 + (((size_t)t * FEAT) + g) * FEAT))[f4];
      acc2[t] += hh.x * dv.x + hh.y * dv.y + hh.z * dv.z + hh.w * dv.w;
    }
  }
  s += acc1;
#pragma unroll
  for (int t = 0; t < T; ++t) s += c[t] * acc2[t];
  out[b * FEAT + g] = s;
}

extern "C" void kernel_launch(void* const* d_in, const int* in_sizes, int n_in,
                              void* d_out, int out_size, void* d_ws, size_t ws_size,
                              hipStream_t stream) {
  const float* x   = (const float*)d_in[0];
  const float* W1  = (const float*)d_in[1];
  const float* b1  = (const float*)d_in[2];
  const float* W2  = (const float*)d_in[3];
  const float* b2  = (const float*)d_in[4];
  const float* mW1 = (const float*)d_in[5];
  const float* mb1 = (const float*)d_in[6];
  const float* mW2 = (const float*)d_in[7];
  const float* mb2 = (const float*)d_in[8];
  const float* dW1 = (const float*)d_in[9];
  const float* db1 = (const float*)d_in[10];
  const float* dW2 = (const float*)d_in[11];
  const float* db2 = (const float*)d_in[12];
  float* out = (float*)d_out;

  float* ws   = (float*)d_ws;
  float* P    = ws;                              // [42][1280][8] = 430080
  float* HP   = P + (size_t)KS * NROWS * B;      // [1280][8] = 10240
  float* H    = HP + 10240;                      // [8][256]
  float* BASE = H + 2048;                        // [8][256]
  float* U    = BASE + 2048;                     // [8][256]
  float* C    = U + 2048;                        // [8][4]

  stage1<<<dim3(KS, NRB), 256, 0, stream>>>(x, W1, dW1, P);
  stage2<<<40, 256, 0, stream>>>(P, b1, db1, HP, KS);
  stage3a<<<1, 256, 0, stream>>>(HP, W2, b2, mW1, mb1, mW2, mb2, H, BASE, C, U);
  stage3b<<<B, 256, 0, stream>>>(H, BASE, C, U, W2, dW2, db2, out);
}

// Round 7
// 241.502 us; speedup vs baseline: 1.5370x; 1.3268x over previous
//
#include <hip/hip_runtime.h>

#define D_IN 150528
#define FEAT 256
#define HID 64
#define T 4
#define B 8
#define NROWS 1280            // 5 * 256 rows (W1 + 4x dW1)
#define D4 37632              // D_IN / 4 float4 per row
#define KS 21                 // K splits
#define JSTEPS 28             // 588 / 21 (64-float4 steps per chunk)
#define RPW 4                 // rows per wave
#define RPB 16                // rows per block (4 waves)
#define NRB 80                // 1280 / 16

// ---------------- stage 1: the 5 batched GEMVs over K=150528 ----------------
// grid (21, 80), block 256 = 4 waves. Wave owns 4 rows; 64 lanes load
// contiguous float4 (1 KB/instr). RPW=4 keeps VGPR ~110 so launch_bounds(,4)
// gives 4 waves/SIMD (2x r6) -> 2x in-flight bytes to hide HBM latency.
__global__ __launch_bounds__(256, 4) void stage1(
    const float* __restrict__ x, const float* __restrict__ W1,
    const float* __restrict__ dW1, float* __restrict__ partial) {
  const int ks   = blockIdx.x;                        // 0..20
  const int rb   = blockIdx.y;                        // 0..79
  const int wid  = threadIdx.x >> 6;                  // wave 0..3
  const int lane = threadIdx.x & 63;
  const int r0   = rb * RPB + wid * RPW;              // this wave's 4 rows
  const int kb4  = ks * (JSTEPS * 64);                // float4 offset in K

  const float4* rp[RPW];
#pragma unroll
  for (int i = 0; i < RPW; ++i) {
    int r = r0 + i, m = r >> 8, f = r & 255;
    const float* base = (m == 0) ? (W1 + (size_t)f * D_IN)
                                 : (dW1 + ((size_t)(m - 1) * FEAT + f) * D_IN);
    rp[i] = (const float4*)base + kb4;
  }
  const float4* x4 = (const float4*)x + kb4;          // + b*D4 + idx

  float acc[RPW][B];
#pragma unroll
  for (int i = 0; i < RPW; ++i)
#pragma unroll
    for (int b = 0; b < B; ++b) acc[i][b] = 0.f;

  for (int j = 0; j < JSTEPS; ++j) {
    const int idx = j * 64 + lane;
    float4 mv[RPW];
#pragma unroll
    for (int i = 0; i < RPW; ++i) mv[i] = rp[i][idx]; // 4x 1KB HBM streams
    float4 xv[B];
#pragma unroll
    for (int b = 0; b < B; ++b) xv[b] = x4[(size_t)b * D4 + idx]; // L1/L2-hot
#pragma unroll
    for (int b = 0; b < B; ++b)
#pragma unroll
      for (int i = 0; i < RPW; ++i)
        acc[i][b] += mv[i].x * xv[b].x + mv[i].y * xv[b].y +
                     mv[i].z * xv[b].z + mv[i].w * xv[b].w;
  }

  // full-wave butterfly per (i,b); lane k (k<32) keeps pair (k>>3, k&7)
  float outv = 0.f;
#pragma unroll
  for (int i = 0; i < RPW; ++i)
#pragma unroll
    for (int b = 0; b < B; ++b) {
      float v = acc[i][b];
      v += __shfl_xor(v, 1);
      v += __shfl_xor(v, 2);
      v += __shfl_xor(v, 4);
      v += __shfl_xor(v, 8);
      v += __shfl_xor(v, 16);
      v += __shfl_xor(v, 32);
      if (lane == i * B + b) outv = v;                // compile-time acc index
    }
  if (lane < RPW * B)                                 // 32 consecutive floats
    partial[((size_t)ks * NROWS + r0) * B + lane] = outv;
}

// ---------------- stage 2: reduce K-splits, add biases ----------------
__global__ __launch_bounds__(256) void stage2(
    const float* __restrict__ partial, const float* __restrict__ b1,
    const float* __restrict__ db1, float* __restrict__ hp) {
  int idx = blockIdx.x * 256 + threadIdx.x;           // 0..10239
  int r = idx >> 3, b = idx & 7;
  int m = r >> 8, f = r & 255;
  float s = (m == 0) ? b1[f] : db1[(m - 1) * FEAT + f];
  for (int ks = 0; ks < KS; ++ks)
    s += partial[((size_t)ks * NROWS + r) * B + b];
  hp[idx] = s;                                        // hp[r][b]
}

// ---------------- stage 3: everything after hpre, one block per batch ------
__global__ __launch_bounds__(256) void stage3(
    const float* __restrict__ hp, const float* __restrict__ W2,
    const float* __restrict__ b2, const float* __restrict__ mW1,
    const float* __restrict__ mb1, const float* __restrict__ mW2,
    const float* __restrict__ mb2, const float* __restrict__ dW2,
    const float* __restrict__ db2, float* __restrict__ out) {
  __shared__ float h_l[FEAT];
  __shared__ float base_l[FEAT];
  __shared__ float u_l[FEAT];
  __shared__ float mid_l[HID];
  __shared__ float c_l[T];
  const int b = blockIdx.x;                           // batch
  const int g = threadIdx.x;                          // feature

  const float hpre = hp[(size_t)g * B + b];
  h_l[g] = hpre > 0.f ? hpre : 0.f;
  __syncthreads();

  // base[g] = b2[g] + h·W2[g]
  const float4* h4 = (const float4*)h_l;
  const float4* w4 = (const float4*)(W2 + (size_t)g * FEAT);
  {
    float s = b2[g];
    for (int f4 = 0; f4 < FEAT / 4; ++f4) {
      float4 hh = h4[f4], w = w4[f4];
      s += hh.x * w.x + hh.y * w.y + hh.z * w.z + hh.w * w.w;
    }
    base_l[g] = s;
  }
  __syncthreads();

  // mid[hid] = relu(mb1 + base·mW1[hid])   (threads 0..63)
  if (g < HID) {
    float s = mb1[g];
    const float4* b4 = (const float4*)base_l;
    const float4* mw = (const float4*)(mW1 + (size_t)g * FEAT);
    for (int f4 = 0; f4 < FEAT / 4; ++f4) {
      float4 bb = b4[f4], w = mw[f4];
      s += bb.x * w.x + bb.y * w.y + bb.z * w.z + bb.w * w.w;
    }
    mid_l[g] = s > 0.f ? s : 0.f;
  }
  __syncthreads();

  // coefs[t]   (threads 0..3)
  if (g < T) {
    float s = mb2[g];
    const float* wrow = mW2 + g * HID;
    for (int hh = 0; hh < HID; ++hh) s += mid_l[hh] * wrow[hh];
    c_l[g] = s;
  }
  __syncthreads();

  // u[g] = (hpre>0) * sum_t c[t]*dhpre[t][g]
  {
    float s = 0.f;
    if (hpre > 0.f) {
#pragma unroll
      for (int t = 0; t < T; ++t)
        s += c_l[t] * hp[((size_t)(1 + t) * FEAT + g) * B + b];
    }
    u_l[g] = s;
  }
  __syncthreads();

  // out[b][g] = base + sum_t c*db2 + u·W2[g] + sum_t c_t*(h·dW2[t][g])
  float o = base_l[g];
#pragma unroll
  for (int t = 0; t < T; ++t) o += c_l[t] * db2[t * FEAT + g];
  const float4* u4 = (const float4*)u_l;
  float a1 = 0.f;
  float a2[T] = {0.f, 0.f, 0.f, 0.f};
  for (int f4 = 0; f4 < FEAT / 4; ++f4) {
    float4 w = w4[f4], uu = u4[f4], hh = h4[f4];
    a1 += uu.x * w.x + uu.y * w.y + uu.z * w.z + uu.w * w.w;
#pragma unroll
    for (int t = 0; t < T; ++t) {
      float4 dv = ((const float4*)(dW2 + (((size_t)t * FEAT) + g) * FEAT))[f4];
      a2[t] += hh.x * dv.x + hh.y * dv.y + hh.z * dv.z + hh.w * dv.w;
    }
  }
  o += a1;
#pragma unroll
  for (int t = 0; t < T; ++t) o += c_l[t] * a2[t];
  out[b * FEAT + g] = o;
}

extern "C" void kernel_launch(void* const* d_in, const int* in_sizes, int n_in,
                              void* d_out, int out_size, void* d_ws, size_t ws_size,
                              hipStream_t stream) {
  const float* x   = (const float*)d_in[0];
  const float* W1  = (const float*)d_in[1];
  const float* b1  = (const float*)d_in[2];
  const float* W2  = (const float*)d_in[3];
  const float* b2  = (const float*)d_in[4];
  const float* mW1 = (const float*)d_in[5];
  const float* mb1 = (const float*)d_in[6];
  const float* mW2 = (const float*)d_in[7];
  const float* mb2 = (const float*)d_in[8];
  const float* dW1 = (const float*)d_in[9];
  const float* db1 = (const float*)d_in[10];
  const float* dW2 = (const float*)d_in[11];
  const float* db2 = (const float*)d_in[12];
  float* out = (float*)d_out;

  float* ws = (float*)d_ws;
  float* P  = ws;                              // [21][1280][8] = 215040
  float* HP = P + (size_t)KS * NROWS * B;      // [1280][8] = 10240

  stage1<<<dim3(KS, NRB), 256, 0, stream>>>(x, W1, dW1, P);
  stage2<<<40, 256, 0, stream>>>(P, b1, db1, HP);
  stage3<<<B, 256, 0, stream>>>(HP, W2, b2, mW1, mb1, mW2, mb2, dW2, db2, out);
}